// Round 4
// baseline (344.848 us; speedup 1.0000x reference)
//
#include <hip/hip_runtime.h>

// LIF recurrence: T timesteps, BN independent neurons.
// mem_{t+1} = (0.5*mem_t + syn_t) * (1 - out_t); syn_{t+1} = in[t]; out_t = mem_t > 1.
// Memory-bound: 210 MB read + 210 MB write, floor ~67 us at 6.3 TB/s achievable.
//
// Round 3 -> 4 change: scalar float, one neuron per thread.
// Evidence trail: lif_kernel never appears in rocprof top-5 (cutoff ~130 us),
// so the kernel is already < 130 us and bench dur_us carries ~230 us of harness
// restore/poison. The only measured kernel win so far was raising wave count
// (float4->float2, -11 us). Scalar gives 2048 blocks = 8 blocks/CU = 32 waves/CU
// (hardware max), doubling wave-level latency hiding; 4B/lane x 64 = 256 B/wave
// accesses are fully coalesced (the 6.4 TB/s poison fill uses 4B/lane stores).
// PF=4 register pipeline keeps 4 loads in flight/wave: 32 waves x 4 x 256 B
// = 32 KB/CU outstanding reads. Normal (cached) loads/stores — match the
// fill's proven 6.4 TB/s store path instead of nontemporal.

constexpr int T_STEPS = 100;
constexpr int PF = 4;  // prefetch distance

__global__ __launch_bounds__(256) void lif_kernel(const float* __restrict__ in,
                                                  float* __restrict__ out,
                                                  int bn) {
    const int i = blockIdx.x * blockDim.x + threadIdx.x;
    if (i >= bn) return;

    const float* __restrict__ ip = in + i;
    float* __restrict__ op = out + i;

    float mem = 0.0f;
    float syn = 0.0f;

    // Prime the 4-deep pipeline: h_0 .. h_3 in flight.
    float hP[PF];
#pragma unroll
    for (int k = 0; k < PF; ++k) {
        hP[k] = ip[(long)k * bn];
    }

#pragma unroll
    for (int t = 0; t < T_STEPS; ++t) {
        // Issue load for t+PF before consuming h_t.
        float hn = 0.0f;
        if (t + PF < T_STEPS) {
            hn = ip[(long)(t + PF) * bn];
        }

        float o = mem > 1.0f ? 1.0f : 0.0f;
        op[(long)t * bn] = o;

        // detach_reset: zero where spiked, else leaky integrate with delayed syn.
        mem = (o != 0.0f) ? 0.0f : fmaf(0.5f, mem, syn);

        const int idx = t % PF;  // static after full unroll
        syn = hP[idx];           // syn_{t+1} = in[t]
        hP[idx] = hn;
    }
}

extern "C" void kernel_launch(void* const* d_in, const int* in_sizes, int n_in,
                              void* d_out, int out_size, void* d_ws, size_t ws_size,
                              hipStream_t stream) {
    const float* in = (const float*)d_in[0];
    float* out = (float*)d_out;

    const int total = in_sizes[0];          // T * B * N
    const int bn = total / T_STEPS;         // B * N = 524288

    const int block = 256;
    const int grid = (bn + block - 1) / block;  // 2048 blocks

    lif_kernel<<<grid, block, 0, stream>>>(in, out, bn);
}

// Round 5
// 330.527 us; speedup vs baseline: 1.0433x; 1.0433x over previous
//
#include <hip/hip_runtime.h>

// LIF recurrence: T timesteps, BN independent neurons.
// mem_{t+1} = (0.5*mem_t + syn_t) * (1 - out_t); syn_{t+1} = in[t]; out_t = mem_t > 1.
// Memory-bound: 210 MB read + 210 MB write, floor ~67 us at 6.3 TB/s achievable.
//
// Round 4 -> 5 change: __syncthreads() every timestep (single-variable A/B vs R1).
// Theory: waves drift apart in t (no sync), so the instantaneous HBM request
// stream is 512-B granules scattered across the whole 420 MB footprint ->
// DRAM row activations serve partial rows -> ~half bandwidth (kernel plateaus
// at ~3.2 TB/s across 4 structurally different variants). Locking the block's
// 4 waves to the same slice makes each block emit 2 KB contiguous granules
// per step. Barrier cost ~2 us total. Prefetch registers carry across the
// barrier; PF=4 keeps loads 4 slices ahead of consumption.

constexpr int T_STEPS = 100;
constexpr int PF = 4;  // prefetch distance

typedef float v2f __attribute__((ext_vector_type(2)));

__global__ __launch_bounds__(256) void lif_kernel(const v2f* __restrict__ in,
                                                  v2f* __restrict__ out,
                                                  int bn2) {
    const int i = blockIdx.x * blockDim.x + threadIdx.x;
    // grid is exact (bn2 % 256 == 0): no early-return, every thread reaches
    // every __syncthreads().

    const v2f* __restrict__ ip = in + i;
    v2f* __restrict__ op = out + i;

    v2f mem = 0.0f;
    v2f syn = 0.0f;

    // Prime the pipeline: h_0 .. h_{PF-1} in flight.
    v2f hP[PF];
#pragma unroll
    for (int k = 0; k < PF; ++k) {
        hP[k] = __builtin_nontemporal_load(ip + (long)k * bn2);
    }

#pragma unroll
    for (int t = 0; t < T_STEPS; ++t) {
        // Issue load for t+PF before consuming h_t.
        v2f hn = 0.0f;
        if (t + PF < T_STEPS) {
            hn = __builtin_nontemporal_load(ip + (long)(t + PF) * bn2);
        }

        v2f o;
        o.x = mem.x > 1.0f ? 1.0f : 0.0f;
        o.y = mem.y > 1.0f ? 1.0f : 0.0f;

        __builtin_nontemporal_store(o, op + (long)t * bn2);

        // detach_reset: zero where spiked, else leaky integrate with delayed syn.
        mem.x = (o.x != 0.0f) ? 0.0f : fmaf(0.5f, mem.x, syn.x);
        mem.y = (o.y != 0.0f) ? 0.0f : fmaf(0.5f, mem.y, syn.y);

        const int idx = t % PF;  // static after full unroll
        syn = hP[idx];           // syn_{t+1} = in[t]
        hP[idx] = hn;

        // Keep all 4 waves of the block on the same timestep slice.
        __syncthreads();
    }
}

extern "C" void kernel_launch(void* const* d_in, const int* in_sizes, int n_in,
                              void* d_out, int out_size, void* d_ws, size_t ws_size,
                              hipStream_t stream) {
    const float* in = (const float*)d_in[0];
    float* out = (float*)d_out;

    const int total = in_sizes[0];          // T * B * N
    const int bn = total / T_STEPS;         // B * N = 524288
    const int bn2 = bn / 2;                 // float2 columns per timestep = 262144

    const int block = 256;
    const int grid = bn2 / block;           // 1024 blocks, exact

    lif_kernel<<<grid, block, 0, stream>>>((const v2f*)in, (v2f*)out, bn2);
}

// Round 6
// 326.740 us; speedup vs baseline: 1.0554x; 1.0116x over previous
//
#include <hip/hip_runtime.h>

// LIF recurrence: T timesteps, BN independent neurons.
// mem_{t+1} = (0.5*mem_t + syn_t) * (1 - out_t); syn_{t+1} = in[t]; out_t = mem_t > 1.
// Memory-bound: 210 MB read + 210 MB write, floor ~67 us at 6.3 TB/s achievable.
//
// Round 5 -> 6 change: chunked read-burst / write-burst structure.
// All five prior variants (width 4/8/16 B, 8-32 waves/CU, PF 2-8, sync/no-sync)
// plateau at kernel ~133 us = 3.2 TB/s. Their shared invariant: 1 load + 1 store
// interleaved 1:1 per iteration -> DRAM channels alternate read/write at fine
// grain -> bus turnaround penalty ~halves bandwidth. (Pure-write fill: 6.4 TB/s;
// unrolled copy: 6.3 TB/s — both present same-direction bursts.)
// Here: 10 chunks of 10 steps. Per chunk: issue 10 back-to-back loads for the
// NEXT chunk, compute 10 steps (vmcnt wait covers only current-chunk loads,
// next-chunk loads stay in flight), then 10 back-to-back stores. Each wave now
// emits 5 KB same-direction bursts. No barrier (would drain vmcnt).

constexpr int T_STEPS = 100;
constexpr int C = 10;                       // timesteps per chunk
constexpr int NCH = T_STEPS / C;            // 10 chunks

typedef float v2f __attribute__((ext_vector_type(2)));

__global__ __launch_bounds__(256) void lif_kernel(const v2f* __restrict__ in,
                                                  v2f* __restrict__ out,
                                                  int bn2) {
    const int i = blockIdx.x * blockDim.x + threadIdx.x;
    if (i >= bn2) return;

    const v2f* __restrict__ ip = in + i;
    v2f* __restrict__ op = out + i;

    v2f mem = 0.0f;
    v2f syn = 0.0f;

    v2f h[C];
    v2f hn[C];
    v2f o[C];

    // Preload chunk 0 as one 10-load burst.
#pragma unroll
    for (int k = 0; k < C; ++k) {
        h[k] = __builtin_nontemporal_load(ip + (long)k * bn2);
    }

#pragma unroll
    for (int c = 0; c < NCH; ++c) {
        // Burst-issue next chunk's 10 loads (no deps — go out back-to-back).
        if (c + 1 < NCH) {
#pragma unroll
            for (int k = 0; k < C; ++k) {
                hn[k] = __builtin_nontemporal_load(ip + (long)((c + 1) * C + k) * bn2);
            }
        }

        // Compute 10 steps; the vmcnt wait here covers only the OLDEST
        // outstanding loads (current chunk), leaving next-chunk loads in flight.
#pragma unroll
        for (int k = 0; k < C; ++k) {
            o[k].x = mem.x > 1.0f ? 1.0f : 0.0f;
            o[k].y = mem.y > 1.0f ? 1.0f : 0.0f;
            // detach_reset: zero where spiked, else leaky integrate of delayed syn.
            mem.x = (o[k].x != 0.0f) ? 0.0f : fmaf(0.5f, mem.x, syn.x);
            mem.y = (o[k].y != 0.0f) ? 0.0f : fmaf(0.5f, mem.y, syn.y);
            syn = h[k];   // syn_{t+1} = in[t]
        }

        // Burst-issue the chunk's 10 stores.
#pragma unroll
        for (int k = 0; k < C; ++k) {
            __builtin_nontemporal_store(o[k], op + (long)(c * C + k) * bn2);
        }

        // Rotate prefetch buffer (pure register renaming after full unroll).
#pragma unroll
        for (int k = 0; k < C; ++k) {
            h[k] = hn[k];
        }
    }
}

extern "C" void kernel_launch(void* const* d_in, const int* in_sizes, int n_in,
                              void* d_out, int out_size, void* d_ws, size_t ws_size,
                              hipStream_t stream) {
    const float* in = (const float*)d_in[0];
    float* out = (float*)d_out;

    const int total = in_sizes[0];          // T * B * N
    const int bn = total / T_STEPS;         // B * N = 524288
    const int bn2 = bn / 2;                 // float2 columns per timestep = 262144

    const int block = 256;
    const int grid = bn2 / block;           // 1024 blocks, exact

    lif_kernel<<<grid, block, 0, stream>>>((const v2f*)in, (v2f*)out, bn2);
}